// Round 9
// baseline (42.622 us; speedup 1.0000x reference)
//
#include <hip/hip_runtime.h>
#include <math.h>

#define EPS 1e-8f

typedef __attribute__((ext_vector_type(8))) short bf16x8;
typedef __attribute__((ext_vector_type(4))) float f32x4;

// ---- ws layout (FLOAT units). frag tile = 1024 bf16 (hi 512 + lo 512) = 512 floats.
#define OFF_F1    0        // L1  cw1 [8 nt][4 kt]
#define OFF_FV1   16384    // V1  ww1 [4][4]
#define OFF_F2    24576    // L2  cw2 [16][4]
#define OFF_FV2   57344    // V2  ww2 [8][2]
#define OFF_F3    65536    // L3  cw3 [2][8]  (20 rows padded to 32)
#define OFF_FV3   73728    // V3  ww3 [1][4]  (10 rows padded to 16)
#define OFF_BASF  75776    // basis A-frags [64 ft] (k 10 padded to 32)

__device__ __forceinline__ unsigned short f2bf(float f){
  unsigned u = __float_as_uint(f);
  return (unsigned short)((u + 0x7fffu + ((u >> 16) & 1u)) >> 16);
}
__device__ __forceinline__ float bf2f(unsigned short h){
  return __uint_as_float(((unsigned)h) << 16);
}
__device__ __forceinline__ int fslot(int s, int kt){
  return s ^ kt ^ (((s >> 4) & 1) << 2);
}

// ---------------------------------------------------------------------------
// prep: B-fragment hi/lo bf16 planes for all six layers + basis A-frags.
// Weight tile (nt,kt), lane s, elem j holds W[nt*16+(s&15)][kt*32+8*(s>>4)+j],
// 0-pad rows >= N. Basis tile ft, lane s: A[f=ft*16+(s&15)][k=8*(s>>4)+j].
// ---------------------------------------------------------------------------
__global__ __launch_bounds__(256) void prep_kernel(
    const float* __restrict__ cw1, const float* __restrict__ cw2, const float* __restrict__ cw3,
    const float* __restrict__ ww1, const float* __restrict__ ww2, const float* __restrict__ ww3,
    float* __restrict__ ws)
{
  int id = blockIdx.x * 256 + threadIdx.x;
  unsigned short* wsU = (unsigned short*)ws;
  if (id < 9472) {
    int t = id >> 6, s = id & 63;
    const float* W; int K, N, tloc, dstF, ktbits;
    if (t < 32)       { W = cw1; K = 128; N = 128; tloc = t;       dstF = OFF_F1;  ktbits = 2; }
    else if (t < 48)  { W = ww1; K = 128; N = 64;  tloc = t - 32;  dstF = OFF_FV1; ktbits = 2; }
    else if (t < 112) { W = cw2; K = 128; N = 256; tloc = t - 48;  dstF = OFF_F2;  ktbits = 2; }
    else if (t < 128) { W = ww2; K = 64;  N = 128; tloc = t - 112; dstF = OFF_FV2; ktbits = 1; }
    else if (t < 144) { W = cw3; K = 256; N = 20;  tloc = t - 128; dstF = OFF_F3;  ktbits = 3; }
    else              { W = ww3; K = 128; N = 10;  tloc = t - 144; dstF = OFF_FV3; ktbits = 2; }
    int kt = tloc & ((1 << ktbits) - 1);
    int nt = tloc >> ktbits;
    int row = nt * 16 + (s & 15);
    int kb  = kt * 32 + 8 * (s >> 4);
    bf16x8 hv, lv;
    #pragma unroll
    for (int j = 0; j < 8; ++j) {
      float v = (row < N) ? W[row * K + kb + j] : 0.f;
      unsigned short h = f2bf(v);
      hv[j] = (short)h;
      lv[j] = (short)f2bf(v - bf2f(h));
    }
    unsigned short* dst = wsU + dstF * 2 + tloc * 1024 + s * 8;
    *(bf16x8*)dst = hv;
    *(bf16x8*)(dst + 512) = lv;
    return;
  }
  id -= 9472;
  if (id < 4096) {   // basis A-frags
    int ft = id >> 6, s = id & 63;
    int f = ft * 16 + (s & 15);
    int k0 = 8 * (s >> 4);
    float tt = (float)f * (1.0f / 1023.0f);
    float v[10]; float sum = 0.f;
    #pragma unroll
    for (int p = 0; p < 10; ++p) {
      float d = tt - (float)p * (1.0f / 9.0f);
      float e = expf(-d * d * 50.0f);
      v[p] = e; sum += e;
    }
    float inv = 1.0f / (sum + EPS);
    bf16x8 hv, lv;
    #pragma unroll
    for (int j = 0; j < 8; ++j) {
      int k = k0 + j;
      float val = (k < 10) ? v[k] * inv : 0.f;
      unsigned short h = f2bf(val);
      hv[j] = (short)h;
      lv[j] = (short)f2bf(val - bf2f(h));
    }
    unsigned short* dst = wsU + OFF_BASF * 2 + ft * 1024 + s * 8;
    *(bf16x8*)dst = hv;
    *(bf16x8*)(dst + 512) = lv;
  }
}

#define MFMA __builtin_amdgcn_mfma_f32_16x16x32_bf16

// ---------------------------------------------------------------------------
// Fully fused, all-MFMA (bf16x3) MLP + MFMA combine + output.
// 32 rows/block, 512 threads (8 waves), grid 512 (2 blocks/CU).
// ---------------------------------------------------------------------------
__global__ __launch_bounds__(512, 4) void fused_kernel(
    const float* __restrict__ x,
    const float* __restrict__ cb1, const float* __restrict__ cb2, const float* __restrict__ cb3,
    const float* __restrict__ wb1, const float* __restrict__ wb2, const float* __restrict__ wb3,
    const float* __restrict__ ws, float* __restrict__ out)
{
  __shared__ unsigned short H2A[16384];   // h2 A-frags [2 mt][8 kt]; [0..8192) aliases XA
  __shared__ unsigned short H1A[8192];    // h1 A-frags [2 mt][4 kt]; later combine B-frags
  __shared__ unsigned short HV1A[4096];   // hv1 A-frags [2 mt][2 kt]
  __shared__ unsigned short HV2A[8192];   // hv2 A-frags [2 mt][4 kt]
  __shared__ float vbuf[320];             // logits -> softmax w [32][10]
  __shared__ float cpbuf[640];            // cp sums -> wm [32][20]

  const int tid = threadIdx.x;
  const int l   = tid & 63;
  const int w   = tid >> 6;     // 0..7
  const int g   = l >> 4;       // 0..3
  const int c16 = l & 15;
  const int b0  = blockIdx.x * 32;
  unsigned short* XA = H2A;     // x A-frags [2 mt][4 kt], dead after B2
  const unsigned short* wsU = (const unsigned short*)ws;

  // ---- P0: load x, split hi/lo, write XA frags
  {
    int r = tid >> 4, k8 = tid & 15;
    const float4* xg = (const float4*)(x + (size_t)(b0 + r) * 128 + k8 * 8);
    float4 v0 = xg[0], v1 = xg[1];
    float xv[8] = {v0.x, v0.y, v0.z, v0.w, v1.x, v1.y, v1.z, v1.w};
    bf16x8 hv, lv;
    #pragma unroll
    for (int j = 0; j < 8; ++j) {
      unsigned short h = f2bf(xv[j]);
      hv[j] = (short)h;
      lv[j] = (short)f2bf(xv[j] - bf2f(h));
    }
    int kt = k8 >> 2;
    int tile = (r >> 4) * 4 + kt;
    int s = (r & 15) + 16 * (k8 & 3);
    unsigned short* dst = XA + tile * 1024 + fslot(s, kt) * 8;
    *(bf16x8*)dst = hv;
    *(bf16x8*)(dst + 512) = lv;
  }

  // P1P2 pointers + kt0 B-frag prefetch (global, legal before barrier)
  const int mt  = w >> 2;            // row tile 0..1
  const int ntv = w & 3;             // V1 col tile
  const int nt0 = (w & 3) * 2, nt1 = nt0 + 1;  // L1 col tiles
  const unsigned short* BV  = wsU + OFF_FV1*2 + (ntv*4)*1024 + l*8;
  const unsigned short* BL0 = wsU + OFF_F1*2  + (nt0*4)*1024 + l*8;
  const unsigned short* BL1 = wsU + OFF_F1*2  + (nt1*4)*1024 + l*8;
  bf16x8 nvh = *(const bf16x8*)BV;        bf16x8 nvl = *(const bf16x8*)(BV + 512);
  bf16x8 n0h = *(const bf16x8*)BL0;       bf16x8 n0l = *(const bf16x8*)(BL0 + 512);
  bf16x8 n1h = *(const bf16x8*)BL1;       bf16x8 n1l = *(const bf16x8*)(BL1 + 512);

  __syncthreads();   // B1: XA ready

  // ---- P1P2: V1 (1 tile) + L1 (2 tiles) fused over kt, B rotated
  {
    float bv  = wb1[ntv*16 + c16];
    float bl0 = cb1[nt0*16 + c16], bl1 = cb1[nt1*16 + c16];
    f32x4 aVA = {bv, bv, bv, bv},     aVB = {0.f, 0.f, 0.f, 0.f};
    f32x4 aL0A = {bl0, bl0, bl0, bl0}, aL0B = {0.f, 0.f, 0.f, 0.f};
    f32x4 aL1A = {bl1, bl1, bl1, bl1}, aL1B = {0.f, 0.f, 0.f, 0.f};
    #pragma unroll
    for (int kt = 0; kt < 4; ++kt) {
      bf16x8 vh = nvh, vl = nvl, b0h_ = n0h, b0l_ = n0l, b1h_ = n1h, b1l_ = n1l;
      if (kt < 3) {
        nvh = *(const bf16x8*)(BV  + (kt+1)*1024); nvl = *(const bf16x8*)(BV  + (kt+1)*1024 + 512);
        n0h = *(const bf16x8*)(BL0 + (kt+1)*1024); n0l = *(const bf16x8*)(BL0 + (kt+1)*1024 + 512);
        n1h = *(const bf16x8*)(BL1 + (kt+1)*1024); n1l = *(const bf16x8*)(BL1 + (kt+1)*1024 + 512);
      }
      const unsigned short* ap = XA + (mt*4 + kt) * 1024 + fslot(l, kt) * 8;
      bf16x8 ah = *(const bf16x8*)ap;
      bf16x8 al = *(const bf16x8*)(ap + 512);
      aVA = MFMA(ah, vh, aVA, 0,0,0);   aVB = MFMA(ah, vl, aVB, 0,0,0);   aVB = MFMA(al, vh, aVB, 0,0,0);
      aL0A = MFMA(ah, b0h_, aL0A, 0,0,0); aL0B = MFMA(ah, b0l_, aL0B, 0,0,0); aL0B = MFMA(al, b0h_, aL0B, 0,0,0);
      aL1A = MFMA(ah, b1h_, aL1A, 0,0,0); aL1B = MFMA(ah, b1l_, aL1B, 0,0,0); aL1B = MFMA(al, b1h_, aL1B, 0,0,0);
    }
    // V1 epilogue -> HV1A (hv1 width 64)
    {
      int kt2 = ntv >> 1;
      int sb = 16 * ((2*ntv + (c16 >> 3)) & 3);
      unsigned short* tb = HV1A + (mt*2 + kt2) * 1024;
      #pragma unroll
      for (int i = 0; i < 4; ++i) {
        float v = fmaxf(aVA[i] + aVB[i], 0.f);
        int idx = fslot(4*g + i + sb, kt2) * 8 + (c16 & 7);
        unsigned short h = f2bf(v);
        tb[idx] = h; tb[512 + idx] = f2bf(v - bf2f(h));
      }
    }
    // L1 epilogue -> H1A (h1 width 128)
    #pragma unroll
    for (int t2 = 0; t2 < 2; ++t2) {
      int nt = nt0 + t2;
      int kt2 = nt >> 1;
      int sb = 16 * ((2*nt + (c16 >> 3)) & 3);
      unsigned short* tb = H1A + (mt*4 + kt2) * 1024;
      #pragma unroll
      for (int i = 0; i < 4; ++i) {
        float v = t2 ? fmaxf(aL1A[i] + aL1B[i], 0.f) : fmaxf(aL0A[i] + aL0B[i], 0.f);
        int idx = fslot(4*g + i + sb, kt2) * 8 + (c16 & 7);
        unsigned short h = f2bf(v);
        tb[idx] = h; tb[512 + idx] = f2bf(v - bf2f(h));
      }
    }
  }

  // P3 B-frag preloads (V2: 2 tiles x 2 kt), issued before the barrier
  const int v0t = (w & 3) * 2, v1t = v0t + 1;   // hv2 col tiles 0..7
  const unsigned short* C0 = wsU + OFF_FV2*2 + (v0t*2)*1024 + l*8;
  const unsigned short* C1 = wsU + OFF_FV2*2 + (v1t*2)*1024 + l*8;
  bf16x8 c0h0 = *(const bf16x8*)C0;          bf16x8 c0l0 = *(const bf16x8*)(C0 + 512);
  bf16x8 c0h1 = *(const bf16x8*)(C0 + 1024); bf16x8 c0l1 = *(const bf16x8*)(C0 + 1536);
  bf16x8 c1h0 = *(const bf16x8*)C1;          bf16x8 c1l0 = *(const bf16x8*)(C1 + 512);
  bf16x8 c1h1 = *(const bf16x8*)(C1 + 1024); bf16x8 c1l1 = *(const bf16x8*)(C1 + 1536);

  __syncthreads();   // B2: H1A/HV1A ready, XA dead

  // ---- P3: V2 (2 tiles/wave, K=64) -> HV2A frags
  {
    float bb0 = wb2[v0t*16 + c16], bb1 = wb2[v1t*16 + c16];
    f32x4 a0A = {bb0, bb0, bb0, bb0}, a0B = {0.f, 0.f, 0.f, 0.f};
    f32x4 a1A = {bb1, bb1, bb1, bb1}, a1B = {0.f, 0.f, 0.f, 0.f};
    {
      const unsigned short* ap = HV1A + (mt*2 + 0) * 1024 + fslot(l, 0) * 8;
      bf16x8 ah = *(const bf16x8*)ap, al = *(const bf16x8*)(ap + 512);
      a0A = MFMA(ah, c0h0, a0A, 0,0,0); a0B = MFMA(ah, c0l0, a0B, 0,0,0); a0B = MFMA(al, c0h0, a0B, 0,0,0);
      a1A = MFMA(ah, c1h0, a1A, 0,0,0); a1B = MFMA(ah, c1l0, a1B, 0,0,0); a1B = MFMA(al, c1h0, a1B, 0,0,0);
    }
    {
      const unsigned short* ap = HV1A + (mt*2 + 1) * 1024 + fslot(l, 1) * 8;
      bf16x8 ah = *(const bf16x8*)ap, al = *(const bf16x8*)(ap + 512);
      a0A = MFMA(ah, c0h1, a0A, 0,0,0); a0B = MFMA(ah, c0l1, a0B, 0,0,0); a0B = MFMA(al, c0h1, a0B, 0,0,0);
      a1A = MFMA(ah, c1h1, a1A, 0,0,0); a1B = MFMA(ah, c1l1, a1B, 0,0,0); a1B = MFMA(al, c1h1, a1B, 0,0,0);
    }
    #pragma unroll
    for (int t2 = 0; t2 < 2; ++t2) {
      int nt = v0t + t2;
      int kt2 = nt >> 1;
      int sb = 16 * ((2*nt + (c16 >> 3)) & 3);
      unsigned short* tb = HV2A + (mt*4 + kt2) * 1024;
      #pragma unroll
      for (int i = 0; i < 4; ++i) {
        float v = t2 ? fmaxf(a1A[i] + a1B[i], 0.f) : fmaxf(a0A[i] + a0B[i], 0.f);
        int idx = fslot(4*g + i + sb, kt2) * 8 + (c16 & 7);
        unsigned short h = f2bf(v);
        tb[idx] = h; tb[512 + idx] = f2bf(v - bf2f(h));
      }
    }
  }

  // ---- P4: L2 (4 tiles/wave in 2 pairs, K=128) -> H2A frags, B rotated
  #pragma unroll
  for (int pp = 0; pp < 2; ++pp) {
    const int m0 = (w & 3) * 4 + pp * 2, m1 = m0 + 1;   // h2 col tiles 0..15
    const unsigned short* D0 = wsU + OFF_F2*2 + (m0*4)*1024 + l*8;
    const unsigned short* D1 = wsU + OFF_F2*2 + (m1*4)*1024 + l*8;
    bf16x8 nd0h = *(const bf16x8*)D0, nd0l = *(const bf16x8*)(D0 + 512);
    bf16x8 nd1h = *(const bf16x8*)D1, nd1l = *(const bf16x8*)(D1 + 512);
    float bb0 = cb2[m0*16 + c16], bb1 = cb2[m1*16 + c16];
    f32x4 a0A = {bb0, bb0, bb0, bb0}, a0B = {0.f, 0.f, 0.f, 0.f};
    f32x4 a1A = {bb1, bb1, bb1, bb1}, a1B = {0.f, 0.f, 0.f, 0.f};
    #pragma unroll
    for (int kt = 0; kt < 4; ++kt) {
      bf16x8 d0h = nd0h, d0l = nd0l, d1h = nd1h, d1l = nd1l;
      if (kt < 3) {
        nd0h = *(const bf16x8*)(D0 + (kt+1)*1024); nd0l = *(const bf16x8*)(D0 + (kt+1)*1024 + 512);
        nd1h = *(const bf16x8*)(D1 + (kt+1)*1024); nd1l = *(const bf16x8*)(D1 + (kt+1)*1024 + 512);
      }
      const unsigned short* ap = H1A + (mt*4 + kt) * 1024 + fslot(l, kt) * 8;
      bf16x8 ah = *(const bf16x8*)ap, al = *(const bf16x8*)(ap + 512);
      a0A = MFMA(ah, d0h, a0A, 0,0,0); a0B = MFMA(ah, d0l, a0B, 0,0,0); a0B = MFMA(al, d0h, a0B, 0,0,0);
      a1A = MFMA(ah, d1h, a1A, 0,0,0); a1B = MFMA(ah, d1l, a1B, 0,0,0); a1B = MFMA(al, d1h, a1B, 0,0,0);
    }
    #pragma unroll
    for (int t2 = 0; t2 < 2; ++t2) {
      int nt = m0 + t2;
      int kt2 = nt >> 1;
      int sb = 16 * ((2*nt + (c16 >> 3)) & 3);
      unsigned short* tb = H2A + (mt*8 + kt2) * 1024;
      #pragma unroll
      for (int i = 0; i < 4; ++i) {
        float v = t2 ? fmaxf(a1A[i] + a1B[i], 0.f) : fmaxf(a0A[i] + a0B[i], 0.f);
        int idx = fslot(4*g + i + sb, kt2) * 8 + (c16 & 7);
        unsigned short h = f2bf(v);
        tb[idx] = h; tb[512 + idx] = f2bf(v - bf2f(h));
      }
    }
  }
  __syncthreads();   // B3: H2A/HV2A ready

  // ---- P5: V3+L3 via MFMA (unique owners -> plain LDS stores)
  if (w < 4) {        // L3: tile (lmt = w>>1, lnt = w&1), K=256
    const int lmt = w >> 1, lnt = w & 1;
    const unsigned short* F3 = wsU + OFF_F3*2 + (lnt*8)*1024 + l*8;
    f32x4 aA = {0.f, 0.f, 0.f, 0.f}, aB = {0.f, 0.f, 0.f, 0.f};
    bf16x8 nbh = *(const bf16x8*)F3, nbl = *(const bf16x8*)(F3 + 512);
    #pragma unroll
    for (int kt = 0; kt < 8; ++kt) {
      bf16x8 bh = nbh, bl = nbl;
      if (kt < 7) {
        nbh = *(const bf16x8*)(F3 + (kt+1)*1024); nbl = *(const bf16x8*)(F3 + (kt+1)*1024 + 512);
      }
      const unsigned short* ap = H2A + (lmt*8 + kt) * 1024 + fslot(l, kt) * 8;
      bf16x8 ah = *(const bf16x8*)ap, al = *(const bf16x8*)(ap + 512);
      aA = MFMA(ah, bh, aA, 0,0,0); aB = MFMA(ah, bl, aB, 0,0,0); aB = MFMA(al, bh, aB, 0,0,0);
    }
    #pragma unroll
    for (int i = 0; i < 4; ++i) {
      int r = lmt*16 + 4*g + i, c = lnt*16 + c16;
      if (c < 20) cpbuf[r*20 + c] = aA[i] + aB[i];
    }
  } else if (w < 6) { // V3: tile (vmt = w-4), K=128
    const int vmt = w - 4;
    const unsigned short* FV = wsU + OFF_FV3*2 + l*8;
    f32x4 aA = {0.f, 0.f, 0.f, 0.f}, aB = {0.f, 0.f, 0.f, 0.f};
    #pragma unroll
    for (int kt = 0; kt < 4; ++kt) {
      bf16x8 bh = *(const bf16x8*)(FV + kt*1024), bl = *(const bf16x8*)(FV + kt*1024 + 512);
      const unsigned short* ap = HV2A + (vmt*4 + kt) * 1024 + fslot(l, kt) * 8;
      bf16x8 ah = *(const bf16x8*)ap, al = *(const bf16x8*)(ap + 512);
      aA = MFMA(ah, bh, aA, 0,0,0); aB = MFMA(ah, bl, aB, 0,0,0); aB = MFMA(al, bh, aB, 0,0,0);
    }
    #pragma unroll
    for (int i = 0; i < 4; ++i) {
      int r = vmt*16 + 4*g + i;
      if (c16 < 10) vbuf[r*10 + c16] = aA[i] + aB[i];
    }
  }
  __syncthreads();   // B4: vbuf(logits) + cpbuf(cp sums) ready

  // ---- P6: softmax + wm (tid<32, one row each)
  if (tid < 32) {
    float lg[10]; float m = -1e30f;
    #pragma unroll
    for (int j = 0; j < 10; ++j) { lg[j] = vbuf[tid*10 + j] + wb3[j]; m = fmaxf(m, lg[j]); }
    float s = 0.f;
    #pragma unroll
    for (int j = 0; j < 10; ++j) { float e = expf(lg[j] - m); lg[j] = e; s += e; }
    float inv = __builtin_amdgcn_rcpf(s);
    #pragma unroll
    for (int j = 0; j < 10; ++j) vbuf[tid*10 + j] = lg[j] * inv;
    #pragma unroll
    for (int p = 0; p < 10; ++p) {
      float s0 = cpbuf[tid*20 + 2*p]     + cb3[2*p];
      float s1 = cpbuf[tid*20 + 2*p + 1] + cb3[2*p + 1];
      float cm = 0.5f * (tanhf(s0) + tanhf(s1));
      cpbuf[tid*20 + p] = vbuf[tid*10 + p] * cm;
    }
  }
  __syncthreads();   // B5: w in vbuf[.][0..10), wm in cpbuf[.*20 + 0..10)

  // ---- P6b: pack combine B-frags (wm: tiles 0,1; w: tiles 2,3) into H1A
  unsigned short* CB = H1A;   // dead since B3; [4 tiles][1024 shorts]
  if (tid < 256) {
    int tile = tid >> 6, s = tid & 63;
    int src = tile >> 1, bt = tile & 1;
    int b = bt * 16 + (s & 15);
    int k0 = 8 * (s >> 4);
    bf16x8 hv, lv;
    #pragma unroll
    for (int j = 0; j < 8; ++j) {
      int k = k0 + j;
      float v = 0.f;
      if (k < 10) v = src ? vbuf[b*10 + k] : cpbuf[b*20 + k];
      unsigned short h = f2bf(v);
      hv[j] = (short)h;
      lv[j] = (short)f2bf(v - bf2f(h));
    }
    unsigned short* dst = CB + tile * 1024 + s * 8;
    *(bf16x8*)dst = hv;
    *(bf16x8*)(dst + 512) = lv;
  }
  __syncthreads();   // B6: combine B-frags ready

  // ---- P7: MFMA combine. wave w: ft = w*8..w*8+7, bt = 0,1.
  // out[b0 + bt*16 + (l&15)][ft*16 + 4g + i] = num/den, float4 stores.
  {
    bf16x8 wm0h = *(const bf16x8*)(CB + 0*1024 + l*8);
    bf16x8 wm0l = *(const bf16x8*)(CB + 0*1024 + 512 + l*8);
    bf16x8 wm1h = *(const bf16x8*)(CB + 1*1024 + l*8);
    bf16x8 wm1l = *(const bf16x8*)(CB + 1*1024 + 512 + l*8);
    bf16x8 w0h  = *(const bf16x8*)(CB + 2*1024 + l*8);
    bf16x8 w0l  = *(const bf16x8*)(CB + 2*1024 + 512 + l*8);
    bf16x8 w1h  = *(const bf16x8*)(CB + 3*1024 + l*8);
    bf16x8 w1l  = *(const bf16x8*)(CB + 3*1024 + 512 + l*8);
    const unsigned short* AP = wsU + OFF_BASF*2 + (w*8)*1024 + l*8;
    bf16x8 nah = *(const bf16x8*)AP;
    bf16x8 nal = *(const bf16x8*)(AP + 512);
    const size_t orow0 = (size_t)(b0 + c16) * 1024 + 4*g;
    #pragma unroll
    for (int t = 0; t < 8; ++t) {
      bf16x8 ah = nah, al = nal;
      if (t < 7) {
        nah = *(const bf16x8*)(AP + (t+1)*1024);
        nal = *(const bf16x8*)(AP + (t+1)*1024 + 512);
      }
      const f32x4 z = {0.f, 0.f, 0.f, 0.f};
      f32x4 n0A = MFMA(ah, wm0h, z, 0,0,0);
      f32x4 n0B = MFMA(ah, wm0l, z, 0,0,0);  n0B = MFMA(al, wm0h, n0B, 0,0,0);
      f32x4 d0A = MFMA(ah, w0h,  z, 0,0,0);
      f32x4 d0B = MFMA(ah, w0l,  z, 0,0,0);  d0B = MFMA(al, w0h,  d0B, 0,0,0);
      f32x4 n1A = MFMA(ah, wm1h, z, 0,0,0);
      f32x4 n1B = MFMA(ah, wm1l, z, 0,0,0);  n1B = MFMA(al, wm1h, n1B, 0,0,0);
      f32x4 d1A = MFMA(ah, w1h,  z, 0,0,0);
      f32x4 d1B = MFMA(ah, w1l,  z, 0,0,0);  d1B = MFMA(al, w1h,  d1B, 0,0,0);
      float4 o0, o1;
      o0.x = (n0A[0]+n0B[0]) * __builtin_amdgcn_rcpf(d0A[0]+d0B[0]+EPS);
      o0.y = (n0A[1]+n0B[1]) * __builtin_amdgcn_rcpf(d0A[1]+d0B[1]+EPS);
      o0.z = (n0A[2]+n0B[2]) * __builtin_amdgcn_rcpf(d0A[2]+d0B[2]+EPS);
      o0.w = (n0A[3]+n0B[3]) * __builtin_amdgcn_rcpf(d0A[3]+d0B[3]+EPS);
      o1.x = (n1A[0]+n1B[0]) * __builtin_amdgcn_rcpf(d1A[0]+d1B[0]+EPS);
      o1.y = (n1A[1]+n1B[1]) * __builtin_amdgcn_rcpf(d1A[1]+d1B[1]+EPS);
      o1.z = (n1A[2]+n1B[2]) * __builtin_amdgcn_rcpf(d1A[2]+d1B[2]+EPS);
      o1.w = (n1A[3]+n1B[3]) * __builtin_amdgcn_rcpf(d1A[3]+d1B[3]+EPS);
      int fcol = (w*8 + t) * 16;
      *(float4*)(out + orow0 + fcol)               = o0;
      *(float4*)(out + orow0 + 16*1024 + fcol)     = o1;
    }
  }
}

// ---------------------------------------------------------------------------
extern "C" void kernel_launch(void* const* d_in, const int* in_sizes, int n_in,
                              void* d_out, int out_size, void* d_ws, size_t ws_size,
                              hipStream_t stream)
{
  const float* x   = (const float*)d_in[0];
  const float* cw1 = (const float*)d_in[1];
  const float* cb1 = (const float*)d_in[2];
  const float* cw2 = (const float*)d_in[3];
  const float* cb2 = (const float*)d_in[4];
  const float* cw3 = (const float*)d_in[5];
  const float* cb3 = (const float*)d_in[6];
  const float* ww1 = (const float*)d_in[7];
  const float* wb1 = (const float*)d_in[8];
  const float* ww2 = (const float*)d_in[9];
  const float* wb2 = (const float*)d_in[10];
  const float* ww3 = (const float*)d_in[11];
  const float* wb3 = (const float*)d_in[12];
  float* ws  = (float*)d_ws;
  float* out = (float*)d_out;

  prep_kernel<<<53, 256, 0, stream>>>(cw1, cw2, cw3, ww1, ww2, ww3, ws);
  fused_kernel<<<512, 512, 0, stream>>>(x, cb1, cb2, cb3, wb1, wb2, wb3, ws, out);
}

// Round 11
// 39.099 us; speedup vs baseline: 1.0901x; 1.0901x over previous
//
#include <hip/hip_runtime.h>
#include <math.h>

#define EPS 1e-8f

typedef __attribute__((ext_vector_type(8))) short bf16x8;
typedef __attribute__((ext_vector_type(4))) float f32x4;

// ---- ws layout (FLOAT units). frag tile = 1024 bf16 (hi 512 + lo 512) = 512 floats.
#define OFF_F1    0        // L1  cw1 [8 nt][4 kt]
#define OFF_FV1   16384    // V1  ww1 [4][4]
#define OFF_F2    24576    // L2  cw2 [16][4]
#define OFF_FV2   57344    // V2  ww2 [8][2]
#define OFF_F3    65536    // L3  cw3 [2][8]  (20 rows padded to 32)
#define OFF_FV3   73728    // V3  ww3 [1][4]  (10 rows padded to 16)
#define OFF_BASIS 75776    // [1024][10] fp32

__device__ __forceinline__ unsigned short f2bf(float f){
  unsigned u = __float_as_uint(f);
  return (unsigned short)((u + 0x7fffu + ((u >> 16) & 1u)) >> 16);
}
__device__ __forceinline__ float bf2f(unsigned short h){
  return __uint_as_float(((unsigned)h) << 16);
}
__device__ __forceinline__ int fslot(int s, int kt){
  return s ^ kt ^ (((s >> 4) & 1) << 2);
}

// ---------------------------------------------------------------------------
// prep: B-fragment hi/lo bf16 planes for all six layers + fp32 basis.
// Tile (nt,kt), lane s, elem j holds W[nt*16+(s&15)][kt*32+8*(s>>4)+j], 0-pad
// rows >= N.
// ---------------------------------------------------------------------------
__global__ __launch_bounds__(256) void prep_kernel(
    const float* __restrict__ cw1, const float* __restrict__ cw2, const float* __restrict__ cw3,
    const float* __restrict__ ww1, const float* __restrict__ ww2, const float* __restrict__ ww3,
    float* __restrict__ ws)
{
  int id = blockIdx.x * 256 + threadIdx.x;
  unsigned short* wsU = (unsigned short*)ws;
  if (id < 9472) {
    int t = id >> 6, s = id & 63;
    const float* W; int K, N, tloc, dstF, ktbits;
    if (t < 32)       { W = cw1; K = 128; N = 128; tloc = t;       dstF = OFF_F1;  ktbits = 2; }
    else if (t < 48)  { W = ww1; K = 128; N = 64;  tloc = t - 32;  dstF = OFF_FV1; ktbits = 2; }
    else if (t < 112) { W = cw2; K = 128; N = 256; tloc = t - 48;  dstF = OFF_F2;  ktbits = 2; }
    else if (t < 128) { W = ww2; K = 64;  N = 128; tloc = t - 112; dstF = OFF_FV2; ktbits = 1; }
    else if (t < 144) { W = cw3; K = 256; N = 20;  tloc = t - 128; dstF = OFF_F3;  ktbits = 3; }
    else              { W = ww3; K = 128; N = 10;  tloc = t - 144; dstF = OFF_FV3; ktbits = 2; }
    int kt = tloc & ((1 << ktbits) - 1);
    int nt = tloc >> ktbits;
    int row = nt * 16 + (s & 15);
    int kb  = kt * 32 + 8 * (s >> 4);
    bf16x8 hv, lv;
    #pragma unroll
    for (int j = 0; j < 8; ++j) {
      float v = (row < N) ? W[row * K + kb + j] : 0.f;
      unsigned short h = f2bf(v);
      hv[j] = (short)h;
      lv[j] = (short)f2bf(v - bf2f(h));
    }
    unsigned short* dst = wsU + dstF * 2 + tloc * 1024 + s * 8;
    *(bf16x8*)dst = hv;
    *(bf16x8*)(dst + 512) = lv;
    return;
  }
  id -= 9472;
  if (id < 1024) {
    int f = id;
    float tt = (float)f * (1.0f / 1023.0f);
    float v[10]; float s = 0.f;
    #pragma unroll
    for (int p = 0; p < 10; ++p) {
      float d = tt - (float)p * (1.0f / 9.0f);
      float e = expf(-d * d * 50.0f);
      v[p] = e; s += e;
    }
    float inv = 1.0f / (s + EPS);
    #pragma unroll
    for (int p = 0; p < 10; ++p) ws[OFF_BASIS + f*10 + p] = v[p] * inv;
  }
}

#define MFMA __builtin_amdgcn_mfma_f32_16x16x32_bf16

// ---------------------------------------------------------------------------
// Fully fused, all-MFMA MLP (bf16x3) + softmax/tanh tail + combine.
// 32 rows/block, 512 threads (8 waves), grid 512 (2 blocks/CU).
// Round-8 verified structure + kt0 prefetch hoists (P4 pp=0, P5) and basis
// load hoist for the tail.
// ---------------------------------------------------------------------------
__global__ __launch_bounds__(512, 4) void fused_kernel(
    const float* __restrict__ x,
    const float* __restrict__ cb1, const float* __restrict__ cb2, const float* __restrict__ cb3,
    const float* __restrict__ wb1, const float* __restrict__ wb2, const float* __restrict__ wb3,
    const float* __restrict__ ws, float* __restrict__ out)
{
  __shared__ unsigned short H2A[16384];   // h2 A-frags [2 mt][8 kt]; [0..8192) aliases XA
  __shared__ unsigned short H1A[8192];    // h1 A-frags [2 mt][4 kt]
  __shared__ unsigned short HV1A[4096];   // hv1 A-frags [2 mt][2 kt]
  __shared__ unsigned short HV2A[8192];   // hv2 A-frags [2 mt][4 kt]
  __shared__ float vbuf[320];             // logits -> softmax w [32][10]
  __shared__ float cpbuf[640];            // cp sums -> wm [32][20]

  const int tid = threadIdx.x;
  const int l   = tid & 63;
  const int w   = tid >> 6;     // 0..7
  const int g   = l >> 4;       // 0..3
  const int c16 = l & 15;
  const int b0  = blockIdx.x * 32;
  unsigned short* XA = H2A;     // x A-frags [2 mt][4 kt], dead after B2
  const unsigned short* wsU = (const unsigned short*)ws;

  // ---- P0: load x, split hi/lo, write XA frags
  {
    int r = tid >> 4, k8 = tid & 15;
    const float4* xg = (const float4*)(x + (size_t)(b0 + r) * 128 + k8 * 8);
    float4 v0 = xg[0], v1 = xg[1];
    float xv[8] = {v0.x, v0.y, v0.z, v0.w, v1.x, v1.y, v1.z, v1.w};
    bf16x8 hv, lv;
    #pragma unroll
    for (int j = 0; j < 8; ++j) {
      unsigned short h = f2bf(xv[j]);
      hv[j] = (short)h;
      lv[j] = (short)f2bf(xv[j] - bf2f(h));
    }
    int kt = k8 >> 2;
    int tile = (r >> 4) * 4 + kt;
    int s = (r & 15) + 16 * (k8 & 3);
    unsigned short* dst = XA + tile * 1024 + fslot(s, kt) * 8;
    *(bf16x8*)dst = hv;
    *(bf16x8*)(dst + 512) = lv;
  }

  // P1P2 pointers + kt0 B-frag prefetch (global, legal before barrier)
  const int mt  = w >> 2;            // row tile 0..1
  const int ntv = w & 3;             // V1 col tile
  const int nt0 = (w & 3) * 2, nt1 = nt0 + 1;  // L1 col tiles
  const unsigned short* BV  = wsU + OFF_FV1*2 + (ntv*4)*1024 + l*8;
  const unsigned short* BL0 = wsU + OFF_F1*2  + (nt0*4)*1024 + l*8;
  const unsigned short* BL1 = wsU + OFF_F1*2  + (nt1*4)*1024 + l*8;
  bf16x8 nvh = *(const bf16x8*)BV;        bf16x8 nvl = *(const bf16x8*)(BV + 512);
  bf16x8 n0h = *(const bf16x8*)BL0;       bf16x8 n0l = *(const bf16x8*)(BL0 + 512);
  bf16x8 n1h = *(const bf16x8*)BL1;       bf16x8 n1l = *(const bf16x8*)(BL1 + 512);

  __syncthreads();   // B1: XA ready

  // ---- P1P2: V1 (1 tile) + L1 (2 tiles) fused over kt, B rotated
  {
    float bv  = wb1[ntv*16 + c16];
    float bl0 = cb1[nt0*16 + c16], bl1 = cb1[nt1*16 + c16];
    f32x4 aVA = {bv, bv, bv, bv},     aVB = {0.f, 0.f, 0.f, 0.f};
    f32x4 aL0A = {bl0, bl0, bl0, bl0}, aL0B = {0.f, 0.f, 0.f, 0.f};
    f32x4 aL1A = {bl1, bl1, bl1, bl1}, aL1B = {0.f, 0.f, 0.f, 0.f};
    #pragma unroll
    for (int kt = 0; kt < 4; ++kt) {
      bf16x8 vh = nvh, vl = nvl, b0h_ = n0h, b0l_ = n0l, b1h_ = n1h, b1l_ = n1l;
      if (kt < 3) {
        nvh = *(const bf16x8*)(BV  + (kt+1)*1024); nvl = *(const bf16x8*)(BV  + (kt+1)*1024 + 512);
        n0h = *(const bf16x8*)(BL0 + (kt+1)*1024); n0l = *(const bf16x8*)(BL0 + (kt+1)*1024 + 512);
        n1h = *(const bf16x8*)(BL1 + (kt+1)*1024); n1l = *(const bf16x8*)(BL1 + (kt+1)*1024 + 512);
      }
      const unsigned short* ap = XA + (mt*4 + kt) * 1024 + fslot(l, kt) * 8;
      bf16x8 ah = *(const bf16x8*)ap;
      bf16x8 al = *(const bf16x8*)(ap + 512);
      aVA = MFMA(ah, vh, aVA, 0,0,0);   aVB = MFMA(ah, vl, aVB, 0,0,0);   aVB = MFMA(al, vh, aVB, 0,0,0);
      aL0A = MFMA(ah, b0h_, aL0A, 0,0,0); aL0B = MFMA(ah, b0l_, aL0B, 0,0,0); aL0B = MFMA(al, b0h_, aL0B, 0,0,0);
      aL1A = MFMA(ah, b1h_, aL1A, 0,0,0); aL1B = MFMA(ah, b1l_, aL1B, 0,0,0); aL1B = MFMA(al, b1h_, aL1B, 0,0,0);
    }
    // V1 epilogue -> HV1A (hv1 width 64)
    {
      int kt2 = ntv >> 1;
      int sb = 16 * ((2*ntv + (c16 >> 3)) & 3);
      unsigned short* tb = HV1A + (mt*2 + kt2) * 1024;
      #pragma unroll
      for (int i = 0; i < 4; ++i) {
        float v = fmaxf(aVA[i] + aVB[i], 0.f);
        int idx = fslot(4*g + i + sb, kt2) * 8 + (c16 & 7);
        unsigned short h = f2bf(v);
        tb[idx] = h; tb[512 + idx] = f2bf(v - bf2f(h));
      }
    }
    // L1 epilogue -> H1A (h1 width 128)
    #pragma unroll
    for (int t2 = 0; t2 < 2; ++t2) {
      int nt = nt0 + t2;
      int kt2 = nt >> 1;
      int sb = 16 * ((2*nt + (c16 >> 3)) & 3);
      unsigned short* tb = H1A + (mt*4 + kt2) * 1024;
      #pragma unroll
      for (int i = 0; i < 4; ++i) {
        float v = t2 ? fmaxf(aL1A[i] + aL1B[i], 0.f) : fmaxf(aL0A[i] + aL0B[i], 0.f);
        int idx = fslot(4*g + i + sb, kt2) * 8 + (c16 & 7);
        unsigned short h = f2bf(v);
        tb[idx] = h; tb[512 + idx] = f2bf(v - bf2f(h));
      }
    }
  }

  // P3 B-frag preloads (V2: 2 tiles x 2 kt), issued before the barrier
  const int v0t = (w & 3) * 2, v1t = v0t + 1;   // hv2 col tiles 0..7
  const unsigned short* C0 = wsU + OFF_FV2*2 + (v0t*2)*1024 + l*8;
  const unsigned short* C1 = wsU + OFF_FV2*2 + (v1t*2)*1024 + l*8;
  bf16x8 c0h0 = *(const bf16x8*)C0;          bf16x8 c0l0 = *(const bf16x8*)(C0 + 512);
  bf16x8 c0h1 = *(const bf16x8*)(C0 + 1024); bf16x8 c0l1 = *(const bf16x8*)(C0 + 1536);
  bf16x8 c1h0 = *(const bf16x8*)C1;          bf16x8 c1l0 = *(const bf16x8*)(C1 + 512);
  bf16x8 c1h1 = *(const bf16x8*)(C1 + 1024); bf16x8 c1l1 = *(const bf16x8*)(C1 + 1536);

  // P4 pp=0 kt0 B-frag prefetch (global, read-only -> safe before barrier)
  const int m0p = (w & 3) * 4, m1p = m0p + 1;
  const unsigned short* D0p = wsU + OFF_F2*2 + (m0p*4)*1024 + l*8;
  const unsigned short* D1p = wsU + OFF_F2*2 + (m1p*4)*1024 + l*8;
  bf16x8 pd0h = *(const bf16x8*)D0p, pd0l = *(const bf16x8*)(D0p + 512);
  bf16x8 pd1h = *(const bf16x8*)D1p, pd1l = *(const bf16x8*)(D1p + 512);

  __syncthreads();   // B2: H1A/HV1A ready, XA dead

  // ---- P3: V2 (2 tiles/wave, K=64) -> HV2A frags
  {
    float bb0 = wb2[v0t*16 + c16], bb1 = wb2[v1t*16 + c16];
    f32x4 a0A = {bb0, bb0, bb0, bb0}, a0B = {0.f, 0.f, 0.f, 0.f};
    f32x4 a1A = {bb1, bb1, bb1, bb1}, a1B = {0.f, 0.f, 0.f, 0.f};
    {
      const unsigned short* ap = HV1A + (mt*2 + 0) * 1024 + fslot(l, 0) * 8;
      bf16x8 ah = *(const bf16x8*)ap, al = *(const bf16x8*)(ap + 512);
      a0A = MFMA(ah, c0h0, a0A, 0,0,0); a0B = MFMA(ah, c0l0, a0B, 0,0,0); a0B = MFMA(al, c0h0, a0B, 0,0,0);
      a1A = MFMA(ah, c1h0, a1A, 0,0,0); a1B = MFMA(ah, c1l0, a1B, 0,0,0); a1B = MFMA(al, c1h0, a1B, 0,0,0);
    }
    {
      const unsigned short* ap = HV1A + (mt*2 + 1) * 1024 + fslot(l, 1) * 8;
      bf16x8 ah = *(const bf16x8*)ap, al = *(const bf16x8*)(ap + 512);
      a0A = MFMA(ah, c0h1, a0A, 0,0,0); a0B = MFMA(ah, c0l1, a0B, 0,0,0); a0B = MFMA(al, c0h1, a0B, 0,0,0);
      a1A = MFMA(ah, c1h1, a1A, 0,0,0); a1B = MFMA(ah, c1l1, a1B, 0,0,0); a1B = MFMA(al, c1h1, a1B, 0,0,0);
    }
    #pragma unroll
    for (int t2 = 0; t2 < 2; ++t2) {
      int nt = v0t + t2;
      int kt2 = nt >> 1;
      int sb = 16 * ((2*nt + (c16 >> 3)) & 3);
      unsigned short* tb = HV2A + (mt*4 + kt2) * 1024;
      #pragma unroll
      for (int i = 0; i < 4; ++i) {
        float v = t2 ? fmaxf(a1A[i] + a1B[i], 0.f) : fmaxf(a0A[i] + a0B[i], 0.f);
        int idx = fslot(4*g + i + sb, kt2) * 8 + (c16 & 7);
        unsigned short h = f2bf(v);
        tb[idx] = h; tb[512 + idx] = f2bf(v - bf2f(h));
      }
    }
  }

  // ---- P4: L2 (4 tiles/wave in 2 pairs, K=128) -> H2A frags, B rotated
  #pragma unroll
  for (int pp = 0; pp < 2; ++pp) {
    const int m0 = (w & 3) * 4 + pp * 2, m1 = m0 + 1;   // h2 col tiles 0..15
    const unsigned short* D0 = wsU + OFF_F2*2 + (m0*4)*1024 + l*8;
    const unsigned short* D1 = wsU + OFF_F2*2 + (m1*4)*1024 + l*8;
    bf16x8 nd0h = pp ? *(const bf16x8*)D0 : pd0h;
    bf16x8 nd0l = pp ? *(const bf16x8*)(D0 + 512) : pd0l;
    bf16x8 nd1h = pp ? *(const bf16x8*)D1 : pd1h;
    bf16x8 nd1l = pp ? *(const bf16x8*)(D1 + 512) : pd1l;
    float bb0 = cb2[m0*16 + c16], bb1 = cb2[m1*16 + c16];
    f32x4 a0A = {bb0, bb0, bb0, bb0}, a0B = {0.f, 0.f, 0.f, 0.f};
    f32x4 a1A = {bb1, bb1, bb1, bb1}, a1B = {0.f, 0.f, 0.f, 0.f};
    #pragma unroll
    for (int kt = 0; kt < 4; ++kt) {
      bf16x8 d0h = nd0h, d0l = nd0l, d1h = nd1h, d1l = nd1l;
      if (kt < 3) {
        nd0h = *(const bf16x8*)(D0 + (kt+1)*1024); nd0l = *(const bf16x8*)(D0 + (kt+1)*1024 + 512);
        nd1h = *(const bf16x8*)(D1 + (kt+1)*1024); nd1l = *(const bf16x8*)(D1 + (kt+1)*1024 + 512);
      }
      const unsigned short* ap = H1A + (mt*4 + kt) * 1024 + fslot(l, kt) * 8;
      bf16x8 ah = *(const bf16x8*)ap, al = *(const bf16x8*)(ap + 512);
      a0A = MFMA(ah, d0h, a0A, 0,0,0); a0B = MFMA(ah, d0l, a0B, 0,0,0); a0B = MFMA(al, d0h, a0B, 0,0,0);
      a1A = MFMA(ah, d1h, a1A, 0,0,0); a1B = MFMA(ah, d1l, a1B, 0,0,0); a1B = MFMA(al, d1h, a1B, 0,0,0);
    }
    #pragma unroll
    for (int t2 = 0; t2 < 2; ++t2) {
      int nt = m0 + t2;
      int kt2 = nt >> 1;
      int sb = 16 * ((2*nt + (c16 >> 3)) & 3);
      unsigned short* tb = H2A + (mt*8 + kt2) * 1024;
      #pragma unroll
      for (int i = 0; i < 4; ++i) {
        float v = t2 ? fmaxf(a1A[i] + a1B[i], 0.f) : fmaxf(a0A[i] + a0B[i], 0.f);
        int idx = fslot(4*g + i + sb, kt2) * 8 + (c16 & 7);
        unsigned short h = f2bf(v);
        tb[idx] = h; tb[512 + idx] = f2bf(v - bf2f(h));
      }
    }
  }

  // P5 kt0 B-frag prefetch + tail basis hoist (global, safe before barrier)
  bf16x8 p5h = {}, p5l = {};
  if (w < 4) {
    const unsigned short* F3p = wsU + OFF_F3*2 + ((w & 1)*8)*1024 + l*8;
    p5h = *(const bf16x8*)F3p; p5l = *(const bf16x8*)(F3p + 512);
  } else if (w < 6) {
    const unsigned short* FVp = wsU + OFF_FV3*2 + l*8;
    p5h = *(const bf16x8*)FVp; p5l = *(const bf16x8*)(FVp + 512);
  }
  const int f0 = tid * 2;
  float bas[20];
  {
    const float4* bp = (const float4*)((ws + OFF_BASIS) + f0 * 10);
    #pragma unroll
    for (int i = 0; i < 5; ++i) {
      float4 v = bp[i];
      bas[4*i+0] = v.x; bas[4*i+1] = v.y; bas[4*i+2] = v.z; bas[4*i+3] = v.w;
    }
  }
  __syncthreads();   // B3: H2A/HV2A ready

  // ---- P5: V3+L3 via MFMA (unique owners -> plain LDS stores)
  if (w < 4) {        // L3: tile (lmt = w>>1, lnt = w&1), K=256
    const int lmt = w >> 1, lnt = w & 1;
    const unsigned short* F3 = wsU + OFF_F3*2 + (lnt*8)*1024 + l*8;
    f32x4 aA = {0.f, 0.f, 0.f, 0.f}, aB = {0.f, 0.f, 0.f, 0.f};
    bf16x8 nbh = p5h, nbl = p5l;
    #pragma unroll
    for (int kt = 0; kt < 8; ++kt) {
      bf16x8 bh = nbh, bl = nbl;
      if (kt < 7) {
        nbh = *(const bf16x8*)(F3 + (kt+1)*1024); nbl = *(const bf16x8*)(F3 + (kt+1)*1024 + 512);
      }
      const unsigned short* ap = H2A + (lmt*8 + kt) * 1024 + fslot(l, kt) * 8;
      bf16x8 ah = *(const bf16x8*)ap, al = *(const bf16x8*)(ap + 512);
      aA = MFMA(ah, bh, aA, 0,0,0); aB = MFMA(ah, bl, aB, 0,0,0); aB = MFMA(al, bh, aB, 0,0,0);
    }
    #pragma unroll
    for (int i = 0; i < 4; ++i) {
      int r = lmt*16 + 4*g + i, c = lnt*16 + c16;
      if (c < 20) cpbuf[r*20 + c] = aA[i] + aB[i];
    }
  } else if (w < 6) { // V3: tile (vmt = w-4), K=128
    const int vmt = w - 4;
    const unsigned short* FV = wsU + OFF_FV3*2 + l*8;
    f32x4 aA = {0.f, 0.f, 0.f, 0.f}, aB = {0.f, 0.f, 0.f, 0.f};
    #pragma unroll
    for (int kt = 0; kt < 4; ++kt) {
      bf16x8 bh = kt ? *(const bf16x8*)(FV + kt*1024) : p5h;
      bf16x8 bl = kt ? *(const bf16x8*)(FV + kt*1024 + 512) : p5l;
      const unsigned short* ap = HV2A + (vmt*4 + kt) * 1024 + fslot(l, kt) * 8;
      bf16x8 ah = *(const bf16x8*)ap, al = *(const bf16x8*)(ap + 512);
      aA = MFMA(ah, bh, aA, 0,0,0); aB = MFMA(ah, bl, aB, 0,0,0); aB = MFMA(al, bh, aB, 0,0,0);
    }
    #pragma unroll
    for (int i = 0; i < 4; ++i) {
      int r = vmt*16 + 4*g + i;
      if (c16 < 10) vbuf[r*10 + c16] = aA[i] + aB[i];
    }
  }
  __syncthreads();   // B4: vbuf(logits) + cpbuf(cp sums) ready

  // ---- P6: softmax + wm (tid<32, one row each)
  if (tid < 32) {
    float lg[10]; float m = -1e30f;
    #pragma unroll
    for (int j = 0; j < 10; ++j) { lg[j] = vbuf[tid*10 + j] + wb3[j]; m = fmaxf(m, lg[j]); }
    float s = 0.f;
    #pragma unroll
    for (int j = 0; j < 10; ++j) { float e = expf(lg[j] - m); lg[j] = e; s += e; }
    float inv = __builtin_amdgcn_rcpf(s);
    #pragma unroll
    for (int j = 0; j < 10; ++j) vbuf[tid*10 + j] = lg[j] * inv;
    #pragma unroll
    for (int p = 0; p < 10; ++p) {
      float s0 = cpbuf[tid*20 + 2*p]     + cb3[2*p];
      float s1 = cpbuf[tid*20 + 2*p + 1] + cb3[2*p + 1];
      float cm = 0.5f * (tanhf(s0) + tanhf(s1));
      cpbuf[tid*20 + p] = vbuf[tid*10 + p] * cm;
    }
  }
  __syncthreads();   // B5: w in vbuf[.][0..10), wm in cpbuf[.*20 + 0..10)

  // ---- P7: combine + output. thread = 2 consecutive f-cols x 32 rows.
  {
    for (int rr = 0; rr < 32; ++rr) {
      float wv[10], wm[10];
      #pragma unroll
      for (int p = 0; p < 10; p += 2) {
        float2 a = *(const float2*)(vbuf + rr*10 + p);
        wv[p] = a.x; wv[p+1] = a.y;
        float2 b = *(const float2*)(cpbuf + rr*20 + p);
        wm[p] = b.x; wm[p+1] = b.y;
      }
      float n0 = 0.f, d0 = EPS, n1 = 0.f, d1 = EPS;
      #pragma unroll
      for (int p = 0; p < 10; ++p) {
        n0 = fmaf(bas[p],      wm[p], n0);
        d0 = fmaf(bas[p],      wv[p], d0);
        n1 = fmaf(bas[10 + p], wm[p], n1);
        d1 = fmaf(bas[10 + p], wv[p], d1);
      }
      float2 o;
      o.x = n0 * __builtin_amdgcn_rcpf(d0);
      o.y = n1 * __builtin_amdgcn_rcpf(d1);
      *(float2*)(out + (size_t)(b0 + rr) * 1024 + f0) = o;
    }
  }
}

// ---------------------------------------------------------------------------
extern "C" void kernel_launch(void* const* d_in, const int* in_sizes, int n_in,
                              void* d_out, int out_size, void* d_ws, size_t ws_size,
                              hipStream_t stream)
{
  const float* x   = (const float*)d_in[0];
  const float* cw1 = (const float*)d_in[1];
  const float* cb1 = (const float*)d_in[2];
  const float* cw2 = (const float*)d_in[3];
  const float* cb2 = (const float*)d_in[4];
  const float* cw3 = (const float*)d_in[5];
  const float* cb3 = (const float*)d_in[6];
  const float* ww1 = (const float*)d_in[7];
  const float* wb1 = (const float*)d_in[8];
  const float* ww2 = (const float*)d_in[9];
  const float* wb2 = (const float*)d_in[10];
  const float* ww3 = (const float*)d_in[11];
  const float* wb3 = (const float*)d_in[12];
  float* ws  = (float*)d_ws;
  float* out = (float*)d_out;

  prep_kernel<<<41, 256, 0, stream>>>(cw1, cw2, cw3, ww1, ww2, ww3, ws);
  fused_kernel<<<512, 512, 0, stream>>>(x, cb1, cb2, cb3, wb1, wb2, wb3, ws, out);
}